// Round 3
// baseline (1668.126 us; speedup 1.0000x reference)
//
#include <hip/hip_runtime.h>
#include <stdint.h>

#define N_NODES 4096
#define NGRAPH 8
#define NPTS 512
#define KNN 64
#define EPSN 1e-5f

typedef _Float16 f16x8 __attribute__((ext_vector_type(8)));
typedef float f32x4 __attribute__((ext_vector_type(4)));

__device__ __forceinline__ unsigned short f2h(float f) {
    _Float16 h = (_Float16)f;   // RNE, v_cvt_f16_f32
    union { _Float16 h; unsigned short u; } cv; cv.h = h;
    return cv.u;
}

// ---------------- kNN: one block per dst point, bitonic sort of 512 (d2,idx) keys ----------------
__global__ __launch_bounds__(256) void knn_kernel(const float* __restrict__ pos, int* __restrict__ knn_out) {
#pragma clang fp contract(off)
    __shared__ float px[NPTS], py[NPTS], pz[NPTS];
    __shared__ unsigned long long keys[NPTS];
    int b = blockIdx.x >> 9;
    int il = blockIdx.x & (NPTS - 1);
    int tid = threadIdx.x;
    for (int n = tid; n < NPTS; n += 256) {
        int base = (b * NPTS + n) * 3;
        px[n] = pos[base]; py[n] = pos[base + 1]; pz[n] = pos[base + 2];
    }
    __syncthreads();
    float xi = px[il], yi = py[il], zi = pz[il];
    for (int n = tid; n < NPTS; n += 256) {
        float dx = px[n] - xi, dy = py[n] - yi, dz = pz[n] - zi;
        float d2 = dx * dx;
        d2 = d2 + dy * dy;
        d2 = d2 + dz * dz;
        keys[n] = (((unsigned long long)__float_as_uint(d2)) << 32) | (unsigned)n;
    }
    for (int k2 = 2; k2 <= NPTS; k2 <<= 1) {
        for (int j = k2 >> 1; j > 0; j >>= 1) {
            __syncthreads();
            for (int t = tid; t < NPTS; t += 256) {
                int ixj = t ^ j;
                if (ixj > t) {
                    unsigned long long a = keys[t], c = keys[ixj];
                    bool up = ((t & k2) == 0);
                    if ((a > c) == up) { keys[t] = c; keys[ixj] = a; }
                }
            }
        }
    }
    __syncthreads();
    if (tid < KNN) {
        int j = (int)(keys[tid] & 0xffffffffu);
        knn_out[(b * NPTS + il) * KNN + tid] = b * NPTS + j;
    }
}

// ---------------- GraphNorm stats: A = mean*ms, S = w/sqrt(var+eps) ----------------
__global__ __launch_bounds__(256) void gn_stats(const float* __restrict__ x, const float* __restrict__ ms,
                                                const float* __restrict__ w, int C,
                                                float* __restrict__ A, float* __restrict__ S) {
    __shared__ float r1[4][64], r2[4][64];
    int b = blockIdx.y;
    int cl = threadIdx.x & 63;
    int c = blockIdx.x * 64 + cl;
    int part = threadIdx.x >> 6;
    float s1 = 0.f, s2 = 0.f;
    if (c < C) {
        for (int n = part; n < NPTS; n += 4) {
            float v = x[(size_t)(b * NPTS + n) * C + c];
            s1 += v; s2 += v * v;
        }
    }
    r1[part][cl] = s1;
    r2[part][cl] = s2;
    __syncthreads();
    if (part == 0 && c < C) {
        s1 = r1[0][cl] + r1[1][cl] + r1[2][cl] + r1[3][cl];
        s2 = r2[0][cl] + r2[1][cl] + r2[2][cl] + r2[3][cl];
        float mean = s1 * (1.f / NPTS);
        float ex2 = s2 * (1.f / NPTS);
        float a = mean * ms[c];
        float var = ex2 - 2.f * a * mean + a * a;   // E[(x - mean*ms)^2]
        A[b * C + c] = a;
        S[b * C + c] = w[c] / sqrtf(var + EPSN);
    }
}

__global__ void gn_apply(const float* __restrict__ x, const float* __restrict__ A, const float* __restrict__ S,
                         const float* __restrict__ bn, int C, float* __restrict__ out, int relu) {
    int idx = blockIdx.x * 256 + threadIdx.x;
    if (idx >= N_NODES * C) return;
    int c = idx % C;
    int n = idx / C;
    int b = n >> 9;
    float v = (x[idx] - A[b * C + c]) * S[b * C + c] + bn[c];
    if (relu) v = fmaxf(v, 0.f);
    out[idx] = v;
}

// ---------------- Per-node MLP1: U = h@w1h + pos@w1p + b1 ; P = pos@w1p ----------------
template<int CIN, int C>
__global__ __launch_bounds__(64) void node_kernel(const float* __restrict__ h, const float* __restrict__ pos,
                                                  const float* __restrict__ w1, const float* __restrict__ b1,
                                                  float* __restrict__ U, float* __restrict__ P) {
    int c = blockIdx.x * 64 + threadIdx.x;
    int n0 = blockIdx.y * 8;
    float acc[8], pacc[8];
    #pragma unroll
    for (int r = 0; r < 8; ++r) { acc[r] = 0.f; pacc[r] = 0.f; }
    for (int d = 0; d < CIN; ++d) {
        float wv = w1[d * C + c];
        #pragma unroll
        for (int r = 0; r < 8; ++r)
            acc[r] += h[(size_t)(n0 + r) * CIN + d] * wv;
    }
    #pragma unroll
    for (int e = 0; e < 3; ++e) {
        float wv = w1[(CIN + e) * C + c];
        #pragma unroll
        for (int r = 0; r < 8; ++r)
            pacc[r] += pos[(n0 + r) * 3 + e] * wv;
    }
    float bv = b1[c];
    #pragma unroll
    for (int r = 0; r < 8; ++r) {
        U[(size_t)(n0 + r) * C + c] = acc[r] + pacc[r] + bv;
        P[(size_t)(n0 + r) * C + c] = pacc[r];
    }
}

// ---------------- w2 (C x C fp32, [k][n]) -> w2T fp16 [n][k] ----------------
__global__ void w2t_kernel(const float* __restrict__ w2, unsigned short* __restrict__ w2t, int C) {
    int idx = blockIdx.x * 256 + threadIdx.x;
    if (idx >= C * C) return;
    int n = idx / C, k = idx % C;
    w2t[idx] = f2h(w2[k * C + n]);
}

// ---------------- Edge MLP2 + scatter-max: per dst node, (64 x C) @ (C x C), col-max ----------------
// One block per dst node; each of 4 waves owns NCT=C/64 column tiles (all C cols covered, no dup).
template<int C>
__global__ __launch_bounds__(256) void edge_kernel(const float* __restrict__ U, const float* __restrict__ P,
                                                   const int* __restrict__ knn, const unsigned short* __restrict__ w2t,
                                                   const float* __restrict__ b2, float* __restrict__ Y) {
    constexpr int NCT = C / 64;          // col tiles per wave (1,2,4,8)
    __shared__ uint4 Tbuf[64 * 5];       // 64 rows x 80B (32 fp16 + 8B pad) per k-chunk
    __shared__ int jn[64];
    int i = blockIdx.x;
    int tid = threadIdx.x;
    int wave = tid >> 6, lane = tid & 63, m = lane & 15, quad = lane >> 4;
    int cw = wave * (NCT * 16);          // wave's column base
    if (tid < 64) jn[tid] = knn[(size_t)i * KNN + tid];
    f32x4 acc[4][NCT];
    f32x4 zero = {0.f, 0.f, 0.f, 0.f};
    #pragma unroll
    for (int rt = 0; rt < 4; ++rt)
        #pragma unroll
        for (int ct = 0; ct < NCT; ++ct)
            acc[rt][ct] = zero;
    int r = tid >> 2;
    int cq = (tid & 3) * 8;
    const float* Prow = P + (size_t)i * C;
    #pragma unroll 1
    for (int s = 0; s < C / 32; ++s) {
        __syncthreads();   // also covers jn visibility on s==0
        {
            int j = jn[r];
            const float4* up = (const float4*)(U + (size_t)j * C + s * 32 + cq);
            const float4* pp = (const float4*)(Prow + s * 32 + cq);
            float4 u0 = up[0], u1 = up[1];
            float4 p0 = pp[0], p1 = pp[1];
            float t0 = fmaxf(u0.x - p0.x, 0.f), t1 = fmaxf(u0.y - p0.y, 0.f);
            float t2 = fmaxf(u0.z - p0.z, 0.f), t3 = fmaxf(u0.w - p0.w, 0.f);
            float t4 = fmaxf(u1.x - p1.x, 0.f), t5 = fmaxf(u1.y - p1.y, 0.f);
            float t6 = fmaxf(u1.z - p1.z, 0.f), t7 = fmaxf(u1.w - p1.w, 0.f);
            uint4 pk;
            pk.x = (unsigned)f2h(t0) | ((unsigned)f2h(t1) << 16);
            pk.y = (unsigned)f2h(t2) | ((unsigned)f2h(t3) << 16);
            pk.z = (unsigned)f2h(t4) | ((unsigned)f2h(t5) << 16);
            pk.w = (unsigned)f2h(t6) | ((unsigned)f2h(t7) << 16);
            Tbuf[r * 5 + (tid & 3)] = pk;
        }
        __syncthreads();
        f16x8 a[4];
        #pragma unroll
        for (int rt = 0; rt < 4; ++rt)
            a[rt] = *(const f16x8*)((const char*)Tbuf + ((rt * 16 + m) * 5 + quad) * 16);
        #pragma unroll
        for (int ct = 0; ct < NCT; ++ct) {
            f16x8 bb = *(const f16x8*)(w2t + (size_t)(cw + ct * 16 + m) * C + s * 32 + quad * 8);
            #pragma unroll
            for (int rt = 0; rt < 4; ++rt)
                acc[rt][ct] = __builtin_amdgcn_mfma_f32_16x16x32_f16(a[rt], bb, acc[rt][ct], 0, 0, 0);
        }
    }
    #pragma unroll
    for (int ct = 0; ct < NCT; ++ct) {
        float vmax = -3.4e38f;
        #pragma unroll
        for (int rt = 0; rt < 4; ++rt) {
            vmax = fmaxf(vmax, acc[rt][ct][0]);
            vmax = fmaxf(vmax, acc[rt][ct][1]);
            vmax = fmaxf(vmax, acc[rt][ct][2]);
            vmax = fmaxf(vmax, acc[rt][ct][3]);
        }
        vmax = fmaxf(vmax, __shfl_xor(vmax, 16));
        vmax = fmaxf(vmax, __shfl_xor(vmax, 32));
        if (quad == 0) {
            int col = cw + ct * 16 + m;
            Y[(size_t)i * C + col] = vmax + b2[col];
        }
    }
}

// ---------------- Classifier: [N,512] @ [512,14] + b ----------------
__global__ __launch_bounds__(256) void cls_kernel(const float* __restrict__ h, const float* __restrict__ w,
                                                  const float* __restrict__ bias, float* __restrict__ out) {
    __shared__ float wl[512 * 14];
    int tid = threadIdx.x;
    for (int idx = tid; idx < 512 * 14; idx += 256) wl[idx] = w[idx];
    __syncthreads();
    if (tid < 224) {
        int nl = tid / 14, c = tid - nl * 14;
        int n = blockIdx.x * 16 + nl;
        float acc = bias[c];
        const float* hr = h + (size_t)n * 512;
        for (int k = 0; k < 512; ++k)
            acc += hr[k] * wl[k * 14 + c];
        out[(size_t)n * 14 + c] = acc;
    }
}

extern "C" void kernel_launch(void* const* d_in, const int* in_sizes, int n_in,
                              void* d_out, int out_size, void* d_ws, size_t ws_size,
                              hipStream_t stream) {
    const float* pos = (const float*)d_in[0];
    const float* gnw[6]; const float* gnb[6]; const float* gnms[6];
    for (int i = 0; i < 6; ++i) {
        gnw[i]  = (const float*)d_in[2 + 3 * i];
        gnb[i]  = (const float*)d_in[3 + 3 * i];
        gnms[i] = (const float*)d_in[4 + 3 * i];
    }
    const float* cw1[5]; const float* cb1[5]; const float* cw2[5]; const float* cb2[5];
    for (int i = 0; i < 5; ++i) {
        cw1[i] = (const float*)d_in[20 + 4 * i];
        cb1[i] = (const float*)d_in[21 + 4 * i];
        cw2[i] = (const float*)d_in[22 + 4 * i];
        cb2[i] = (const float*)d_in[23 + 4 * i];
    }
    const float* clsw = (const float*)d_in[40];
    const float* clsb = (const float*)d_in[41];
    float* out = (float*)d_out;

    char* ws = (char*)d_ws;
    int* knn            = (int*)(ws + 0);                 // 1 MB
    float* U            = (float*)(ws + 1048576);         // 8 MB
    float* P            = (float*)(ws + 9437184);         // 8 MB
    float* h            = (float*)(ws + 17825792);        // 8 MB
    float* y            = (float*)(ws + 26214400);        // 8 MB
    float* Aa           = (float*)(ws + 34603008);        // 16 KB
    float* Sa           = (float*)(ws + 34619392);        // 16 KB
    unsigned short* w2t = (unsigned short*)(ws + 34635776); // 512 KB

    knn_kernel<<<N_NODES, 256, 0, stream>>>(pos, knn);

    // gn1 on pos -> h [N,3] (no relu)
    gn_stats<<<dim3(1, NGRAPH), 256, 0, stream>>>(pos, gnms[0], gnw[0], 3, Aa, Sa);
    gn_apply<<<(N_NODES * 3 + 255) / 256, 256, 0, stream>>>(pos, Aa, Sa, gnb[0], 3, h, 0);

    // Layer 1: CIN=3, C=64
    node_kernel<3, 64><<<dim3(1, N_NODES / 8), 64, 0, stream>>>(h, pos, cw1[0], cb1[0], U, P);
    w2t_kernel<<<(64 * 64 + 255) / 256, 256, 0, stream>>>(cw2[0], w2t, 64);
    edge_kernel<64><<<N_NODES, 256, 0, stream>>>(U, P, knn, w2t, cb2[0], y);
    gn_stats<<<dim3(1, NGRAPH), 256, 0, stream>>>(y, gnms[1], gnw[1], 64, Aa, Sa);
    gn_apply<<<(N_NODES * 64) / 256, 256, 0, stream>>>(y, Aa, Sa, gnb[1], 64, h, 1);

    // Layer 2: CIN=64, C=128
    node_kernel<64, 128><<<dim3(2, N_NODES / 8), 64, 0, stream>>>(h, pos, cw1[1], cb1[1], U, P);
    w2t_kernel<<<(128 * 128 + 255) / 256, 256, 0, stream>>>(cw2[1], w2t, 128);
    edge_kernel<128><<<N_NODES, 256, 0, stream>>>(U, P, knn, w2t, cb2[1], y);
    gn_stats<<<dim3(2, NGRAPH), 256, 0, stream>>>(y, gnms[2], gnw[2], 128, Aa, Sa);
    gn_apply<<<(N_NODES * 128) / 256, 256, 0, stream>>>(y, Aa, Sa, gnb[2], 128, h, 1);

    // Layer 3: CIN=128, C=256
    node_kernel<128, 256><<<dim3(4, N_NODES / 8), 64, 0, stream>>>(h, pos, cw1[2], cb1[2], U, P);
    w2t_kernel<<<(256 * 256 + 255) / 256, 256, 0, stream>>>(cw2[2], w2t, 256);
    edge_kernel<256><<<N_NODES, 256, 0, stream>>>(U, P, knn, w2t, cb2[2], y);
    gn_stats<<<dim3(4, NGRAPH), 256, 0, stream>>>(y, gnms[3], gnw[3], 256, Aa, Sa);
    gn_apply<<<(N_NODES * 256) / 256, 256, 0, stream>>>(y, Aa, Sa, gnb[3], 256, h, 1);

    // Layer 4: CIN=256, C=512
    node_kernel<256, 512><<<dim3(8, N_NODES / 8), 64, 0, stream>>>(h, pos, cw1[3], cb1[3], U, P);
    w2t_kernel<<<(512 * 512 + 255) / 256, 256, 0, stream>>>(cw2[3], w2t, 512);
    edge_kernel<512><<<N_NODES, 256, 0, stream>>>(U, P, knn, w2t, cb2[3], y);
    gn_stats<<<dim3(8, NGRAPH), 256, 0, stream>>>(y, gnms[4], gnw[4], 512, Aa, Sa);
    gn_apply<<<(N_NODES * 512) / 256, 256, 0, stream>>>(y, Aa, Sa, gnb[4], 512, h, 1);

    // Layer 5: CIN=512, C=512
    node_kernel<512, 512><<<dim3(8, N_NODES / 8), 64, 0, stream>>>(h, pos, cw1[4], cb1[4], U, P);
    w2t_kernel<<<(512 * 512 + 255) / 256, 256, 0, stream>>>(cw2[4], w2t, 512);
    edge_kernel<512><<<N_NODES, 256, 0, stream>>>(U, P, knn, w2t, cb2[4], y);
    gn_stats<<<dim3(8, NGRAPH), 256, 0, stream>>>(y, gnms[5], gnw[5], 512, Aa, Sa);
    gn_apply<<<(N_NODES * 512) / 256, 256, 0, stream>>>(y, Aa, Sa, gnb[5], 512, h, 1);

    cls_kernel<<<N_NODES / 16, 256, 0, stream>>>(h, clsw, clsb, out);
}

// Round 4
// 1104.949 us; speedup vs baseline: 1.5097x; 1.5097x over previous
//
#include <hip/hip_runtime.h>
#include <stdint.h>

#define N_NODES 4096
#define NGRAPH 8
#define NPTS 512
#define KNN 64
#define EPSN 1e-5f

typedef _Float16 f16x8 __attribute__((ext_vector_type(8)));
typedef float f32x4 __attribute__((ext_vector_type(4)));

__device__ __forceinline__ unsigned short f2h(float f) {
    _Float16 h = (_Float16)f;   // RNE, v_cvt_f16_f32
    union { _Float16 h; unsigned short u; } cv; cv.h = h;
    return cv.u;
}

// ---------------- kNN: one block per dst point, bitonic sort of 512 (d2,idx) keys ----------------
__global__ __launch_bounds__(256) void knn_kernel(const float* __restrict__ pos, int* __restrict__ knn_out) {
#pragma clang fp contract(off)
    __shared__ float px[NPTS], py[NPTS], pz[NPTS];
    __shared__ unsigned long long keys[NPTS];
    int b = blockIdx.x >> 9;
    int il = blockIdx.x & (NPTS - 1);
    int tid = threadIdx.x;
    for (int n = tid; n < NPTS; n += 256) {
        int base = (b * NPTS + n) * 3;
        px[n] = pos[base]; py[n] = pos[base + 1]; pz[n] = pos[base + 2];
    }
    __syncthreads();
    float xi = px[il], yi = py[il], zi = pz[il];
    for (int n = tid; n < NPTS; n += 256) {
        float dx = px[n] - xi, dy = py[n] - yi, dz = pz[n] - zi;
        float d2 = dx * dx;
        d2 = d2 + dy * dy;
        d2 = d2 + dz * dz;
        keys[n] = (((unsigned long long)__float_as_uint(d2)) << 32) | (unsigned)n;
    }
    for (int k2 = 2; k2 <= NPTS; k2 <<= 1) {
        for (int j = k2 >> 1; j > 0; j >>= 1) {
            __syncthreads();
            for (int t = tid; t < NPTS; t += 256) {
                int ixj = t ^ j;
                if (ixj > t) {
                    unsigned long long a = keys[t], c = keys[ixj];
                    bool up = ((t & k2) == 0);
                    if ((a > c) == up) { keys[t] = c; keys[ixj] = a; }
                }
            }
        }
    }
    __syncthreads();
    if (tid < KNN) {
        int j = (int)(keys[tid] & 0xffffffffu);
        knn_out[(b * NPTS + il) * KNN + tid] = b * NPTS + j;
    }
}

// ---------------- GraphNorm stats: A = mean*ms, S = w/sqrt(var+eps) ----------------
__global__ __launch_bounds__(256) void gn_stats(const float* __restrict__ x, const float* __restrict__ ms,
                                                const float* __restrict__ w, int C,
                                                float* __restrict__ A, float* __restrict__ S) {
    __shared__ float r1[4][64], r2[4][64];
    int b = blockIdx.y;
    int cl = threadIdx.x & 63;
    int c = blockIdx.x * 64 + cl;
    int part = threadIdx.x >> 6;
    float s1 = 0.f, s2 = 0.f;
    if (c < C) {
        for (int n = part; n < NPTS; n += 4) {
            float v = x[(size_t)(b * NPTS + n) * C + c];
            s1 += v; s2 += v * v;
        }
    }
    r1[part][cl] = s1;
    r2[part][cl] = s2;
    __syncthreads();
    if (part == 0 && c < C) {
        s1 = r1[0][cl] + r1[1][cl] + r1[2][cl] + r1[3][cl];
        s2 = r2[0][cl] + r2[1][cl] + r2[2][cl] + r2[3][cl];
        float mean = s1 * (1.f / NPTS);
        float ex2 = s2 * (1.f / NPTS);
        float a = mean * ms[c];
        float var = ex2 - 2.f * a * mean + a * a;   // E[(x - mean*ms)^2]
        A[b * C + c] = a;
        S[b * C + c] = w[c] / sqrtf(var + EPSN);
    }
}

__global__ void gn_apply(const float* __restrict__ x, const float* __restrict__ A, const float* __restrict__ S,
                         const float* __restrict__ bn, int C, float* __restrict__ out, int relu) {
    int idx = blockIdx.x * 256 + threadIdx.x;
    if (idx >= N_NODES * C) return;
    int c = idx % C;
    int n = idx / C;
    int b = n >> 9;
    float v = (x[idx] - A[b * C + c]) * S[b * C + c] + bn[c];
    if (relu) v = fmaxf(v, 0.f);
    out[idx] = v;
}

// ---------------- Per-node MLP1: U = h@w1h + pos@w1p + b1 ; P = pos@w1p ----------------
template<int CIN, int C>
__global__ __launch_bounds__(64) void node_kernel(const float* __restrict__ h, const float* __restrict__ pos,
                                                  const float* __restrict__ w1, const float* __restrict__ b1,
                                                  float* __restrict__ U, float* __restrict__ P) {
    int c = blockIdx.x * 64 + threadIdx.x;
    int n0 = blockIdx.y * 8;
    float acc[8], pacc[8];
    #pragma unroll
    for (int r = 0; r < 8; ++r) { acc[r] = 0.f; pacc[r] = 0.f; }
    for (int d = 0; d < CIN; ++d) {
        float wv = w1[d * C + c];
        #pragma unroll
        for (int r = 0; r < 8; ++r)
            acc[r] += h[(size_t)(n0 + r) * CIN + d] * wv;
    }
    #pragma unroll
    for (int e = 0; e < 3; ++e) {
        float wv = w1[(CIN + e) * C + c];
        #pragma unroll
        for (int r = 0; r < 8; ++r)
            pacc[r] += pos[(n0 + r) * 3 + e] * wv;
    }
    float bv = b1[c];
    #pragma unroll
    for (int r = 0; r < 8; ++r) {
        U[(size_t)(n0 + r) * C + c] = acc[r] + pacc[r] + bv;
        P[(size_t)(n0 + r) * C + c] = pacc[r];
    }
}

// ---------------- w2 (C x C fp32, [k][n]) -> blocked fp16 layout ----------------
// dst[(ctg*(C/32)+s)*512 + quad*128 + m*8 + j]  where n = ctg*16+m, k = s*32+quad*8+j
// => a wave's B-fragment load (16 lanes m x 4 quads, 16B each) is 1KB fully contiguous.
__global__ void w2tt_kernel(const float* __restrict__ w2, unsigned short* __restrict__ w2t, int C) {
    int idx = blockIdx.x * 256 + threadIdx.x;
    if (idx >= C * C) return;
    int k = idx / C, n = idx % C;
    int dst = ((n >> 4) * (C / 32) + (k >> 5)) * 512 + ((k >> 3) & 3) * 128 + (n & 15) * 8 + (k & 7);
    w2t[dst] = f2h(w2[idx]);
}

// ---------------- Edge MLP2 + scatter-max ----------------
// One block per dst node. W waves; wave w owns cols [w*NCT*16, (w+1)*NCT*16). acc = 4xNCT f32x4 (<=64 regs).
template<int C, int W>
__global__ __launch_bounds__(W * 64, 4) void edge_kernel(const float* __restrict__ U, const float* __restrict__ P,
                                                         const int* __restrict__ knn, const unsigned short* __restrict__ w2t,
                                                         const float* __restrict__ b2, float* __restrict__ Y) {
    constexpr int NCT = C / (W * 16);    // col tiles per wave
    constexpr int EPT = 32 / W;          // staging cols per thread (8 or 4)
    __shared__ unsigned short Tb[64 * 40];   // 64 rows x (32 + 8 pad) halves = 5120B
    __shared__ int jn[64];
    const int i = blockIdx.x;
    const int tid = threadIdx.x;
    const int wave = tid >> 6, lane = tid & 63, m = lane & 15, quad = lane >> 4;
    const int cw = wave * (NCT * 16);
    if (tid < 64) jn[tid] = knn[(size_t)i * KNN + tid];
    f32x4 acc[4][NCT];
    f32x4 zero = {0.f, 0.f, 0.f, 0.f};
    #pragma unroll
    for (int rt = 0; rt < 4; ++rt)
        #pragma unroll
        for (int ct = 0; ct < NCT; ++ct)
            acc[rt][ct] = zero;
    const int rr = tid / W;              // staging row 0..63
    const int c0 = (tid % W) * EPT;      // staging col base
    const float* Prow = P + (size_t)i * C;
    #pragma unroll 1
    for (int s = 0; s < C / 32; ++s) {
        __syncthreads();   // also covers jn visibility on s==0
        {
            int j = jn[rr];
            const float* up = U + (size_t)j * C + s * 32 + c0;
            const float* pp = Prow + s * 32 + c0;
            if constexpr (EPT == 8) {
                float4 u0 = ((const float4*)up)[0], u1 = ((const float4*)up)[1];
                float4 p0 = ((const float4*)pp)[0], p1 = ((const float4*)pp)[1];
                uint4 pk;
                pk.x = (unsigned)f2h(fmaxf(u0.x - p0.x, 0.f)) | ((unsigned)f2h(fmaxf(u0.y - p0.y, 0.f)) << 16);
                pk.y = (unsigned)f2h(fmaxf(u0.z - p0.z, 0.f)) | ((unsigned)f2h(fmaxf(u0.w - p0.w, 0.f)) << 16);
                pk.z = (unsigned)f2h(fmaxf(u1.x - p1.x, 0.f)) | ((unsigned)f2h(fmaxf(u1.y - p1.y, 0.f)) << 16);
                pk.w = (unsigned)f2h(fmaxf(u1.z - p1.z, 0.f)) | ((unsigned)f2h(fmaxf(u1.w - p1.w, 0.f)) << 16);
                *(uint4*)&Tb[rr * 40 + c0] = pk;
            } else {
                float4 u0 = ((const float4*)up)[0];
                float4 p0 = ((const float4*)pp)[0];
                uint2 pk;
                pk.x = (unsigned)f2h(fmaxf(u0.x - p0.x, 0.f)) | ((unsigned)f2h(fmaxf(u0.y - p0.y, 0.f)) << 16);
                pk.y = (unsigned)f2h(fmaxf(u0.z - p0.z, 0.f)) | ((unsigned)f2h(fmaxf(u0.w - p0.w, 0.f)) << 16);
                *(uint2*)&Tb[rr * 40 + c0] = pk;
            }
        }
        __syncthreads();
        f16x8 a[4];
        #pragma unroll
        for (int rt = 0; rt < 4; ++rt)
            a[rt] = *(const f16x8*)&Tb[(rt * 16 + m) * 40 + quad * 8];
        #pragma unroll
        for (int ct = 0; ct < NCT; ++ct) {
            const f16x8 bb = *(const f16x8*)(w2t +
                (size_t)(((cw >> 4) + ct) * (C / 32) + s) * 512 + quad * 128 + m * 8);
            #pragma unroll
            for (int rt = 0; rt < 4; ++rt)
                acc[rt][ct] = __builtin_amdgcn_mfma_f32_16x16x32_f16(a[rt], bb, acc[rt][ct], 0, 0, 0);
        }
    }
    #pragma unroll
    for (int ct = 0; ct < NCT; ++ct) {
        float vmax = -3.4e38f;
        #pragma unroll
        for (int rt = 0; rt < 4; ++rt) {
            vmax = fmaxf(vmax, acc[rt][ct][0]);
            vmax = fmaxf(vmax, acc[rt][ct][1]);
            vmax = fmaxf(vmax, acc[rt][ct][2]);
            vmax = fmaxf(vmax, acc[rt][ct][3]);
        }
        vmax = fmaxf(vmax, __shfl_xor(vmax, 16));
        vmax = fmaxf(vmax, __shfl_xor(vmax, 32));
        if (quad == 0) {
            int col = cw + ct * 16 + m;
            Y[(size_t)i * C + col] = vmax + b2[col];
        }
    }
}

// ---------------- Classifier: [N,512] @ [512,14] + b ----------------
__global__ __launch_bounds__(256) void cls_kernel(const float* __restrict__ h, const float* __restrict__ w,
                                                  const float* __restrict__ bias, float* __restrict__ out) {
    __shared__ float wl[512 * 14];
    int tid = threadIdx.x;
    for (int idx = tid; idx < 512 * 14; idx += 256) wl[idx] = w[idx];
    __syncthreads();
    if (tid < 224) {
        int nl = tid / 14, c = tid - nl * 14;
        int n = blockIdx.x * 16 + nl;
        float acc = bias[c];
        const float* hr = h + (size_t)n * 512;
        for (int k = 0; k < 512; ++k)
            acc += hr[k] * wl[k * 14 + c];
        out[(size_t)n * 14 + c] = acc;
    }
}

extern "C" void kernel_launch(void* const* d_in, const int* in_sizes, int n_in,
                              void* d_out, int out_size, void* d_ws, size_t ws_size,
                              hipStream_t stream) {
    const float* pos = (const float*)d_in[0];
    const float* gnw[6]; const float* gnb[6]; const float* gnms[6];
    for (int i = 0; i < 6; ++i) {
        gnw[i]  = (const float*)d_in[2 + 3 * i];
        gnb[i]  = (const float*)d_in[3 + 3 * i];
        gnms[i] = (const float*)d_in[4 + 3 * i];
    }
    const float* cw1[5]; const float* cb1[5]; const float* cw2[5]; const float* cb2[5];
    for (int i = 0; i < 5; ++i) {
        cw1[i] = (const float*)d_in[20 + 4 * i];
        cb1[i] = (const float*)d_in[21 + 4 * i];
        cw2[i] = (const float*)d_in[22 + 4 * i];
        cb2[i] = (const float*)d_in[23 + 4 * i];
    }
    const float* clsw = (const float*)d_in[40];
    const float* clsb = (const float*)d_in[41];
    float* out = (float*)d_out;

    char* ws = (char*)d_ws;
    int* knn            = (int*)(ws + 0);                 // 1 MB
    float* U            = (float*)(ws + 1048576);         // 8 MB
    float* P            = (float*)(ws + 9437184);         // 8 MB
    float* h            = (float*)(ws + 17825792);        // 8 MB
    float* y            = (float*)(ws + 26214400);        // 8 MB
    float* Aa           = (float*)(ws + 34603008);        // 16 KB
    float* Sa           = (float*)(ws + 34619392);        // 16 KB
    unsigned short* w2t = (unsigned short*)(ws + 34635776); // 512 KB

    knn_kernel<<<N_NODES, 256, 0, stream>>>(pos, knn);

    // gn1 on pos -> h [N,3] (no relu)
    gn_stats<<<dim3(1, NGRAPH), 256, 0, stream>>>(pos, gnms[0], gnw[0], 3, Aa, Sa);
    gn_apply<<<(N_NODES * 3 + 255) / 256, 256, 0, stream>>>(pos, Aa, Sa, gnb[0], 3, h, 0);

    // Layer 1: CIN=3, C=64
    node_kernel<3, 64><<<dim3(1, N_NODES / 8), 64, 0, stream>>>(h, pos, cw1[0], cb1[0], U, P);
    w2tt_kernel<<<(64 * 64 + 255) / 256, 256, 0, stream>>>(cw2[0], w2t, 64);
    edge_kernel<64, 4><<<N_NODES, 256, 0, stream>>>(U, P, knn, w2t, cb2[0], y);
    gn_stats<<<dim3(1, NGRAPH), 256, 0, stream>>>(y, gnms[1], gnw[1], 64, Aa, Sa);
    gn_apply<<<(N_NODES * 64) / 256, 256, 0, stream>>>(y, Aa, Sa, gnb[1], 64, h, 1);

    // Layer 2: CIN=64, C=128
    node_kernel<64, 128><<<dim3(2, N_NODES / 8), 64, 0, stream>>>(h, pos, cw1[1], cb1[1], U, P);
    w2tt_kernel<<<(128 * 128 + 255) / 256, 256, 0, stream>>>(cw2[1], w2t, 128);
    edge_kernel<128, 4><<<N_NODES, 256, 0, stream>>>(U, P, knn, w2t, cb2[1], y);
    gn_stats<<<dim3(2, NGRAPH), 256, 0, stream>>>(y, gnms[2], gnw[2], 128, Aa, Sa);
    gn_apply<<<(N_NODES * 128) / 256, 256, 0, stream>>>(y, Aa, Sa, gnb[2], 128, h, 1);

    // Layer 3: CIN=128, C=256
    node_kernel<128, 256><<<dim3(4, N_NODES / 8), 64, 0, stream>>>(h, pos, cw1[2], cb1[2], U, P);
    w2tt_kernel<<<(256 * 256 + 255) / 256, 256, 0, stream>>>(cw2[2], w2t, 256);
    edge_kernel<256, 4><<<N_NODES, 256, 0, stream>>>(U, P, knn, w2t, cb2[2], y);
    gn_stats<<<dim3(4, NGRAPH), 256, 0, stream>>>(y, gnms[3], gnw[3], 256, Aa, Sa);
    gn_apply<<<(N_NODES * 256) / 256, 256, 0, stream>>>(y, Aa, Sa, gnb[3], 256, h, 1);

    // Layer 4: CIN=256, C=512
    node_kernel<256, 512><<<dim3(8, N_NODES / 8), 64, 0, stream>>>(h, pos, cw1[3], cb1[3], U, P);
    w2tt_kernel<<<(512 * 512 + 255) / 256, 256, 0, stream>>>(cw2[3], w2t, 512);
    edge_kernel<512, 8><<<N_NODES, 512, 0, stream>>>(U, P, knn, w2t, cb2[3], y);
    gn_stats<<<dim3(8, NGRAPH), 256, 0, stream>>>(y, gnms[4], gnw[4], 512, Aa, Sa);
    gn_apply<<<(N_NODES * 512) / 256, 256, 0, stream>>>(y, Aa, Sa, gnb[4], 512, h, 1);

    // Layer 5: CIN=512, C=512
    node_kernel<512, 512><<<dim3(8, N_NODES / 8), 64, 0, stream>>>(h, pos, cw1[4], cb1[4], U, P);
    w2tt_kernel<<<(512 * 512 + 255) / 256, 256, 0, stream>>>(cw2[4], w2t, 512);
    edge_kernel<512, 8><<<N_NODES, 512, 0, stream>>>(U, P, knn, w2t, cb2[4], y);
    gn_stats<<<dim3(8, NGRAPH), 256, 0, stream>>>(y, gnms[5], gnw[5], 512, Aa, Sa);
    gn_apply<<<(N_NODES * 512) / 256, 256, 0, stream>>>(y, Aa, Sa, gnb[5], 512, h, 1);

    cls_kernel<<<N_NODES / 16, 256, 0, stream>>>(h, clsw, clsb, out);
}

// Round 5
// 1079.708 us; speedup vs baseline: 1.5450x; 1.0234x over previous
//
#include <hip/hip_runtime.h>
#include <stdint.h>

#define N_NODES 4096
#define NGRAPH 8
#define NPTS 512
#define KNN 64
#define EPSN 1e-5f

typedef _Float16 f16x8 __attribute__((ext_vector_type(8)));
typedef float f32x4 __attribute__((ext_vector_type(4)));

__device__ __forceinline__ unsigned short f2h(float f) {
    _Float16 h = (_Float16)f;   // RNE, v_cvt_f16_f32
    union { _Float16 h; unsigned short u; } cv; cv.h = h;
    return cv.u;
}

// ---------------- kNN: one block per dst point, bitonic sort of 512 (d2,idx) keys ----------------
__global__ __launch_bounds__(256) void knn_kernel(const float* __restrict__ pos, int* __restrict__ knn_out) {
#pragma clang fp contract(off)
    __shared__ float px[NPTS], py[NPTS], pz[NPTS];
    __shared__ unsigned long long keys[NPTS];
    int b = blockIdx.x >> 9;
    int il = blockIdx.x & (NPTS - 1);
    int tid = threadIdx.x;
    for (int n = tid; n < NPTS; n += 256) {
        int base = (b * NPTS + n) * 3;
        px[n] = pos[base]; py[n] = pos[base + 1]; pz[n] = pos[base + 2];
    }
    __syncthreads();
    float xi = px[il], yi = py[il], zi = pz[il];
    for (int n = tid; n < NPTS; n += 256) {
        float dx = px[n] - xi, dy = py[n] - yi, dz = pz[n] - zi;
        float d2 = dx * dx;
        d2 = d2 + dy * dy;
        d2 = d2 + dz * dz;
        keys[n] = (((unsigned long long)__float_as_uint(d2)) << 32) | (unsigned)n;
    }
    for (int k2 = 2; k2 <= NPTS; k2 <<= 1) {
        for (int j = k2 >> 1; j > 0; j >>= 1) {
            __syncthreads();
            for (int t = tid; t < NPTS; t += 256) {
                int ixj = t ^ j;
                if (ixj > t) {
                    unsigned long long a = keys[t], c = keys[ixj];
                    bool up = ((t & k2) == 0);
                    if ((a > c) == up) { keys[t] = c; keys[ixj] = a; }
                }
            }
        }
    }
    __syncthreads();
    if (tid < KNN) {
        int j = (int)(keys[tid] & 0xffffffffu);
        knn_out[(b * NPTS + il) * KNN + tid] = b * NPTS + j;
    }
}

// ---------------- GraphNorm fused: stats + apply (+optional relu) ----------------
// grid = ((C+63)/64, NGRAPH), block = 256 (4 parts x 64 channels)
__global__ __launch_bounds__(256) void gn_fused(const float* __restrict__ x, const float* __restrict__ ms,
                                                const float* __restrict__ w, const float* __restrict__ bn,
                                                int C, float* __restrict__ out, int relu) {
    __shared__ float r1[4][64], r2[4][64];
    __shared__ float As[64], Ss[64];
    int b = blockIdx.y;
    int cl = threadIdx.x & 63;
    int c = blockIdx.x * 64 + cl;
    int part = threadIdx.x >> 6;
    float s1 = 0.f, s2 = 0.f;
    if (c < C) {
        for (int n = part; n < NPTS; n += 4) {
            float v = x[(size_t)(b * NPTS + n) * C + c];
            s1 += v; s2 += v * v;
        }
    }
    r1[part][cl] = s1;
    r2[part][cl] = s2;
    __syncthreads();
    if (part == 0 && c < C) {
        s1 = r1[0][cl] + r1[1][cl] + r1[2][cl] + r1[3][cl];
        s2 = r2[0][cl] + r2[1][cl] + r2[2][cl] + r2[3][cl];
        float mean = s1 * (1.f / NPTS);
        float ex2 = s2 * (1.f / NPTS);
        float a = mean * ms[c];
        float var = ex2 - 2.f * a * mean + a * a;   // E[(x - mean*ms)^2]
        As[cl] = a;
        Ss[cl] = w[c] / sqrtf(var + EPSN);
    }
    __syncthreads();
    if (c < C) {
        float a = As[cl], sf = Ss[cl], bb = bn[c];
        for (int n = part; n < NPTS; n += 4) {
            size_t idx = (size_t)(b * NPTS + n) * C + c;
            float v = (x[idx] - a) * sf + bb;
            if (relu) v = fmaxf(v, 0.f);
            out[idx] = v;
        }
    }
}

// ---------------- Per-node MLP1: U = h@w1h + pos@w1p + b1 ; P = pos@w1p ----------------
template<int CIN, int C>
__global__ __launch_bounds__(64) void node_kernel(const float* __restrict__ h, const float* __restrict__ pos,
                                                  const float* __restrict__ w1, const float* __restrict__ b1,
                                                  float* __restrict__ U, float* __restrict__ P) {
    int c = blockIdx.x * 64 + threadIdx.x;
    int n0 = blockIdx.y * 8;
    float acc[8], pacc[8];
    #pragma unroll
    for (int r = 0; r < 8; ++r) { acc[r] = 0.f; pacc[r] = 0.f; }
    #pragma unroll 4
    for (int d = 0; d < CIN; ++d) {
        float wv = w1[d * C + c];
        #pragma unroll
        for (int r = 0; r < 8; ++r)
            acc[r] += h[(size_t)(n0 + r) * CIN + d] * wv;
    }
    #pragma unroll
    for (int e = 0; e < 3; ++e) {
        float wv = w1[(CIN + e) * C + c];
        #pragma unroll
        for (int r = 0; r < 8; ++r)
            pacc[r] += pos[(n0 + r) * 3 + e] * wv;
    }
    float bv = b1[c];
    #pragma unroll
    for (int r = 0; r < 8; ++r) {
        U[(size_t)(n0 + r) * C + c] = acc[r] + pacc[r] + bv;
        P[(size_t)(n0 + r) * C + c] = pacc[r];
    }
}

// ---------------- w2 (C x C fp32, [k][n]) -> blocked fp16 layout ----------------
// dst[(ctg*(C/32)+s)*512 + quad*128 + m*8 + j]  where n = ctg*16+m, k = s*32+quad*8+j
__global__ void w2tt_kernel(const float* __restrict__ w2, unsigned short* __restrict__ w2t, int C) {
    int idx = blockIdx.x * 256 + threadIdx.x;
    if (idx >= C * C) return;
    int k = idx / C, n = idx % C;
    int dst = ((n >> 4) * (C / 32) + (k >> 5)) * 512 + ((k >> 3) & 3) * 128 + (n & 15) * 8 + (k & 7);
    w2t[dst] = f2h(w2[idx]);
}

// ---------------- Edge MLP2 + scatter-max ----------------
// One block per dst node. W waves; wave w owns cols [w*NCT*16,(w+1)*NCT*16).
// Register prefetch of next s-chunk + LDS double buffer -> one barrier per iter.
template<int C, int W>
__global__ __launch_bounds__(W * 64, 4) void edge_kernel(const float* __restrict__ U, const float* __restrict__ P,
                                                         const int* __restrict__ knn, const unsigned short* __restrict__ w2t,
                                                         const float* __restrict__ b2, float* __restrict__ Y) {
    constexpr int NCT = C / (W * 16);    // col tiles per wave
    constexpr int EPT = 32 / W;          // staging cols per thread (8 or 4)
    constexpr int S = C / 32;            // k-chunks
    __shared__ unsigned short Tb[2][64 * 40];   // double-buffered 64 x (32+8 pad) halves
    __shared__ int jn[64];
    const int i = blockIdx.x;
    const int tid = threadIdx.x;
    const int wave = tid >> 6, lane = tid & 63, m = lane & 15, quad = lane >> 4;
    const int cw = wave * (NCT * 16);
    if (tid < 64) jn[tid] = knn[(size_t)i * KNN + tid];
    f32x4 acc[4][NCT];
    f32x4 zero = {0.f, 0.f, 0.f, 0.f};
    #pragma unroll
    for (int rt = 0; rt < 4; ++rt)
        #pragma unroll
        for (int ct = 0; ct < NCT; ++ct)
            acc[rt][ct] = zero;
    const int rr = tid / W;              // staging row 0..63
    const int c0 = (tid % W) * EPT;      // staging col base
    __syncthreads();                     // jn visible
    const float* up = U + (size_t)jn[rr] * C + c0;
    const float* pp = P + (size_t)i * C + c0;
    float4 u0, u1, p0, p1;
    u0 = ((const float4*)up)[0]; p0 = ((const float4*)pp)[0];
    if constexpr (EPT == 8) { u1 = ((const float4*)up)[1]; p1 = ((const float4*)pp)[1]; }
    #pragma unroll 2
    for (int s = 0; s < S; ++s) {
        unsigned short* tb = Tb[s & 1];
        if constexpr (EPT == 8) {
            uint4 pk;
            pk.x = (unsigned)f2h(fmaxf(u0.x - p0.x, 0.f)) | ((unsigned)f2h(fmaxf(u0.y - p0.y, 0.f)) << 16);
            pk.y = (unsigned)f2h(fmaxf(u0.z - p0.z, 0.f)) | ((unsigned)f2h(fmaxf(u0.w - p0.w, 0.f)) << 16);
            pk.z = (unsigned)f2h(fmaxf(u1.x - p1.x, 0.f)) | ((unsigned)f2h(fmaxf(u1.y - p1.y, 0.f)) << 16);
            pk.w = (unsigned)f2h(fmaxf(u1.z - p1.z, 0.f)) | ((unsigned)f2h(fmaxf(u1.w - p1.w, 0.f)) << 16);
            *(uint4*)&tb[rr * 40 + c0] = pk;
        } else {
            uint2 pk;
            pk.x = (unsigned)f2h(fmaxf(u0.x - p0.x, 0.f)) | ((unsigned)f2h(fmaxf(u0.y - p0.y, 0.f)) << 16);
            pk.y = (unsigned)f2h(fmaxf(u0.z - p0.z, 0.f)) | ((unsigned)f2h(fmaxf(u0.w - p0.w, 0.f)) << 16);
            *(uint2*)&tb[rr * 40 + c0] = pk;
        }
        if (s + 1 < S) {                 // prefetch next chunk; latency overlaps barrier+MFMA
            u0 = ((const float4*)(up + (s + 1) * 32))[0];
            p0 = ((const float4*)(pp + (s + 1) * 32))[0];
            if constexpr (EPT == 8) {
                u1 = ((const float4*)(up + (s + 1) * 32))[1];
                p1 = ((const float4*)(pp + (s + 1) * 32))[1];
            }
        }
        __syncthreads();
        f16x8 a[4];
        #pragma unroll
        for (int rt = 0; rt < 4; ++rt)
            a[rt] = *(const f16x8*)&tb[(rt * 16 + m) * 40 + quad * 8];
        #pragma unroll
        for (int ct = 0; ct < NCT; ++ct) {
            const f16x8 bb = *(const f16x8*)(w2t +
                (size_t)(((cw >> 4) + ct) * (C / 32) + s) * 512 + quad * 128 + m * 8);
            #pragma unroll
            for (int rt = 0; rt < 4; ++rt)
                acc[rt][ct] = __builtin_amdgcn_mfma_f32_16x16x32_f16(a[rt], bb, acc[rt][ct], 0, 0, 0);
        }
    }
    #pragma unroll
    for (int ct = 0; ct < NCT; ++ct) {
        float vmax = -3.4e38f;
        #pragma unroll
        for (int rt = 0; rt < 4; ++rt) {
            vmax = fmaxf(vmax, acc[rt][ct][0]);
            vmax = fmaxf(vmax, acc[rt][ct][1]);
            vmax = fmaxf(vmax, acc[rt][ct][2]);
            vmax = fmaxf(vmax, acc[rt][ct][3]);
        }
        vmax = fmaxf(vmax, __shfl_xor(vmax, 16));
        vmax = fmaxf(vmax, __shfl_xor(vmax, 32));
        if (quad == 0) {
            int col = cw + ct * 16 + m;
            Y[(size_t)i * C + col] = vmax + b2[col];
        }
    }
}

// ---------------- Classifier: [N,512] @ [512,14] + b ----------------
__global__ __launch_bounds__(256) void cls_kernel(const float* __restrict__ h, const float* __restrict__ w,
                                                  const float* __restrict__ bias, float* __restrict__ out) {
    __shared__ float wl[512 * 14];
    int tid = threadIdx.x;
    for (int idx = tid; idx < 512 * 14; idx += 256) wl[idx] = w[idx];
    __syncthreads();
    if (tid < 224) {
        int nl = tid / 14, c = tid - nl * 14;
        int n = blockIdx.x * 16 + nl;
        float acc = bias[c];
        const float* hr = h + (size_t)n * 512;
        for (int k = 0; k < 512; ++k)
            acc += hr[k] * wl[k * 14 + c];
        out[(size_t)n * 14 + c] = acc;
    }
}

extern "C" void kernel_launch(void* const* d_in, const int* in_sizes, int n_in,
                              void* d_out, int out_size, void* d_ws, size_t ws_size,
                              hipStream_t stream) {
    const float* pos = (const float*)d_in[0];
    const float* gnw[6]; const float* gnb[6]; const float* gnms[6];
    for (int i = 0; i < 6; ++i) {
        gnw[i]  = (const float*)d_in[2 + 3 * i];
        gnb[i]  = (const float*)d_in[3 + 3 * i];
        gnms[i] = (const float*)d_in[4 + 3 * i];
    }
    const float* cw1[5]; const float* cb1[5]; const float* cw2[5]; const float* cb2[5];
    for (int i = 0; i < 5; ++i) {
        cw1[i] = (const float*)d_in[20 + 4 * i];
        cb1[i] = (const float*)d_in[21 + 4 * i];
        cw2[i] = (const float*)d_in[22 + 4 * i];
        cb2[i] = (const float*)d_in[23 + 4 * i];
    }
    const float* clsw = (const float*)d_in[40];
    const float* clsb = (const float*)d_in[41];
    float* out = (float*)d_out;

    char* ws = (char*)d_ws;
    int* knn            = (int*)(ws + 0);                 // 1 MB
    float* U            = (float*)(ws + 1048576);         // 8 MB
    float* P            = (float*)(ws + 9437184);         // 8 MB
    float* h            = (float*)(ws + 17825792);        // 8 MB
    float* y            = (float*)(ws + 26214400);        // 8 MB
    unsigned short* w2t = (unsigned short*)(ws + 34635776); // 512 KB

    knn_kernel<<<N_NODES, 256, 0, stream>>>(pos, knn);

    // gn1 on pos -> h [N,3] (no relu)
    gn_fused<<<dim3(1, NGRAPH), 256, 0, stream>>>(pos, gnms[0], gnw[0], gnb[0], 3, h, 0);

    // Layer 1: CIN=3, C=64
    node_kernel<3, 64><<<dim3(1, N_NODES / 8), 64, 0, stream>>>(h, pos, cw1[0], cb1[0], U, P);
    w2tt_kernel<<<(64 * 64 + 255) / 256, 256, 0, stream>>>(cw2[0], w2t, 64);
    edge_kernel<64, 4><<<N_NODES, 256, 0, stream>>>(U, P, knn, w2t, cb2[0], y);
    gn_fused<<<dim3(1, NGRAPH), 256, 0, stream>>>(y, gnms[1], gnw[1], gnb[1], 64, h, 1);

    // Layer 2: CIN=64, C=128
    node_kernel<64, 128><<<dim3(2, N_NODES / 8), 64, 0, stream>>>(h, pos, cw1[1], cb1[1], U, P);
    w2tt_kernel<<<(128 * 128 + 255) / 256, 256, 0, stream>>>(cw2[1], w2t, 128);
    edge_kernel<128, 8><<<N_NODES, 512, 0, stream>>>(U, P, knn, w2t, cb2[1], y);
    gn_fused<<<dim3(2, NGRAPH), 256, 0, stream>>>(y, gnms[2], gnw[2], gnb[2], 128, h, 1);

    // Layer 3: CIN=128, C=256
    node_kernel<128, 256><<<dim3(4, N_NODES / 8), 64, 0, stream>>>(h, pos, cw1[2], cb1[2], U, P);
    w2tt_kernel<<<(256 * 256 + 255) / 256, 256, 0, stream>>>(cw2[2], w2t, 256);
    edge_kernel<256, 8><<<N_NODES, 512, 0, stream>>>(U, P, knn, w2t, cb2[2], y);
    gn_fused<<<dim3(4, NGRAPH), 256, 0, stream>>>(y, gnms[3], gnw[3], gnb[3], 256, h, 1);

    // Layer 4: CIN=256, C=512
    node_kernel<256, 512><<<dim3(8, N_NODES / 8), 64, 0, stream>>>(h, pos, cw1[3], cb1[3], U, P);
    w2tt_kernel<<<(512 * 512 + 255) / 256, 256, 0, stream>>>(cw2[3], w2t, 512);
    edge_kernel<512, 8><<<N_NODES, 512, 0, stream>>>(U, P, knn, w2t, cb2[3], y);
    gn_fused<<<dim3(8, NGRAPH), 256, 0, stream>>>(y, gnms[4], gnw[4], gnb[4], 512, h, 1);

    // Layer 5: CIN=512, C=512
    node_kernel<512, 512><<<dim3(8, N_NODES / 8), 64, 0, stream>>>(h, pos, cw1[4], cb1[4], U, P);
    w2tt_kernel<<<(512 * 512 + 255) / 256, 256, 0, stream>>>(cw2[4], w2t, 512);
    edge_kernel<512, 8><<<N_NODES, 512, 0, stream>>>(U, P, knn, w2t, cb2[4], y);
    gn_fused<<<dim3(8, NGRAPH), 256, 0, stream>>>(y, gnms[5], gnw[5], gnb[5], 512, h, 1);

    cls_kernel<<<N_NODES / 16, 256, 0, stream>>>(h, clsw, clsb, out);
}

// Round 6
// 974.960 us; speedup vs baseline: 1.7110x; 1.1074x over previous
//
#include <hip/hip_runtime.h>
#include <stdint.h>

#define N_NODES 4096
#define NGRAPH 8
#define NPTS 512
#define KNN 64
#define EPSN 1e-5f

typedef _Float16 f16x8 __attribute__((ext_vector_type(8)));
typedef float f32x4 __attribute__((ext_vector_type(4)));

__device__ __forceinline__ unsigned short f2h(float f) {
    _Float16 h = (_Float16)f;   // RNE, v_cvt_f16_f32
    union { _Float16 h; unsigned short u; } cv; cv.h = h;
    return cv.u;
}

// ---------------- kNN: one block per dst point, bitonic sort of 512 (d2,idx) keys ----------------
__global__ __launch_bounds__(256) void knn_kernel(const float* __restrict__ pos, int* __restrict__ knn_out) {
#pragma clang fp contract(off)
    __shared__ float px[NPTS], py[NPTS], pz[NPTS];
    __shared__ unsigned long long keys[NPTS];
    int b = blockIdx.x >> 9;
    int il = blockIdx.x & (NPTS - 1);
    int tid = threadIdx.x;
    for (int n = tid; n < NPTS; n += 256) {
        int base = (b * NPTS + n) * 3;
        px[n] = pos[base]; py[n] = pos[base + 1]; pz[n] = pos[base + 2];
    }
    __syncthreads();
    float xi = px[il], yi = py[il], zi = pz[il];
    for (int n = tid; n < NPTS; n += 256) {
        float dx = px[n] - xi, dy = py[n] - yi, dz = pz[n] - zi;
        float d2 = dx * dx;
        d2 = d2 + dy * dy;
        d2 = d2 + dz * dz;
        keys[n] = (((unsigned long long)__float_as_uint(d2)) << 32) | (unsigned)n;
    }
    for (int k2 = 2; k2 <= NPTS; k2 <<= 1) {
        for (int j = k2 >> 1; j > 0; j >>= 1) {
            __syncthreads();
            for (int t = tid; t < NPTS; t += 256) {
                int ixj = t ^ j;
                if (ixj > t) {
                    unsigned long long a = keys[t], c = keys[ixj];
                    bool up = ((t & k2) == 0);
                    if ((a > c) == up) { keys[t] = c; keys[ixj] = a; }
                }
            }
        }
    }
    __syncthreads();
    if (tid < KNN) {
        int j = (int)(keys[tid] & 0xffffffffu);
        knn_out[(b * NPTS + il) * KNN + tid] = b * NPTS + j;
    }
}

// ---------------- GraphNorm fused: stats + apply (+optional relu) ----------------
__global__ __launch_bounds__(256) void gn_fused(const float* __restrict__ x, const float* __restrict__ ms,
                                                const float* __restrict__ w, const float* __restrict__ bn,
                                                int C, float* __restrict__ out, int relu) {
    __shared__ float r1[4][64], r2[4][64];
    __shared__ float As[64], Ss[64];
    int b = blockIdx.y;
    int cl = threadIdx.x & 63;
    int c = blockIdx.x * 64 + cl;
    int part = threadIdx.x >> 6;
    float s1 = 0.f, s2 = 0.f;
    if (c < C) {
        for (int n = part; n < NPTS; n += 4) {
            float v = x[(size_t)(b * NPTS + n) * C + c];
            s1 += v; s2 += v * v;
        }
    }
    r1[part][cl] = s1;
    r2[part][cl] = s2;
    __syncthreads();
    if (part == 0 && c < C) {
        s1 = r1[0][cl] + r1[1][cl] + r1[2][cl] + r1[3][cl];
        s2 = r2[0][cl] + r2[1][cl] + r2[2][cl] + r2[3][cl];
        float mean = s1 * (1.f / NPTS);
        float ex2 = s2 * (1.f / NPTS);
        float a = mean * ms[c];
        float var = ex2 - 2.f * a * mean + a * a;   // E[(x - mean*ms)^2]
        As[cl] = a;
        Ss[cl] = w[c] / sqrtf(var + EPSN);
    }
    __syncthreads();
    if (c < C) {
        float a = As[cl], sf = Ss[cl], bb = bn[c];
        for (int n = part; n < NPTS; n += 4) {
            size_t idx = (size_t)(b * NPTS + n) * C + c;
            float v = (x[idx] - a) * sf + bb;
            if (relu) v = fmaxf(v, 0.f);
            out[idx] = v;
        }
    }
}

// ---------------- Per-node MLP1 v2: each block computes 16 rows x ALL C cols ----------------
// h fetched exactly once; w1 stays L2-hot. LDS-staged h chunk, wave-uniform broadcast reads.
template<int CIN, int C>
__global__ __launch_bounds__(C) void node_kernel(const float* __restrict__ h, const float* __restrict__ pos,
                                                 const float* __restrict__ w1, const float* __restrict__ b1,
                                                 float* __restrict__ U, float* __restrict__ P) {
    constexpr int ROWS = 16;
    constexpr int KC = 64;
    constexpr int LDH = KC + 4;
    __shared__ float hs[ROWS][LDH];   // 4352 B
    const int c = threadIdx.x;
    const int n0 = blockIdx.x * ROWS;
    float acc[ROWS];
    #pragma unroll
    for (int r = 0; r < ROWS; ++r) acc[r] = 0.f;
    constexpr int NCHUNK = (CIN + KC - 1) / KC;
    #pragma unroll 1
    for (int s = 0; s < NCHUNK; ++s) {
        const int k0 = s * KC;
        const int kc = (CIN - k0 < KC) ? (CIN - k0) : KC;
        __syncthreads();
        for (int idx = c; idx < ROWS * kc; idx += C) {
            int r = idx / kc, k = idx - r * kc;
            hs[r][k] = h[(size_t)(n0 + r) * CIN + k0 + k];
        }
        __syncthreads();
        int k = 0;
        for (; k + 4 <= kc; k += 4) {
            float w0 = w1[(size_t)(k0 + k) * C + c];
            float w1v = w1[(size_t)(k0 + k + 1) * C + c];
            float w2v = w1[(size_t)(k0 + k + 2) * C + c];
            float w3v = w1[(size_t)(k0 + k + 3) * C + c];
            #pragma unroll
            for (int r = 0; r < ROWS; ++r) {
                f32x4 hv = *(const f32x4*)&hs[r][k];
                acc[r] = fmaf(hv[0], w0, acc[r]);
                acc[r] = fmaf(hv[1], w1v, acc[r]);
                acc[r] = fmaf(hv[2], w2v, acc[r]);
                acc[r] = fmaf(hv[3], w3v, acc[r]);
            }
        }
        for (; k < kc; ++k) {
            float wv = w1[(size_t)(k0 + k) * C + c];
            #pragma unroll
            for (int r = 0; r < ROWS; ++r)
                acc[r] = fmaf(hs[r][k], wv, acc[r]);
        }
    }
    // pos part: P = pos @ w1p (3 k's), U = acc + P + b1
    float pacc[ROWS];
    #pragma unroll
    for (int r = 0; r < ROWS; ++r) pacc[r] = 0.f;
    #pragma unroll
    for (int e = 0; e < 3; ++e) {
        float wv = w1[(size_t)(CIN + e) * C + c];
        #pragma unroll
        for (int r = 0; r < ROWS; ++r)
            pacc[r] = fmaf(pos[(n0 + r) * 3 + e], wv, pacc[r]);
    }
    float bv = b1[c];
    #pragma unroll
    for (int r = 0; r < ROWS; ++r) {
        U[(size_t)(n0 + r) * C + c] = acc[r] + pacc[r] + bv;
        P[(size_t)(n0 + r) * C + c] = pacc[r];
    }
}

// ---------------- w2 (C x C fp32, [k][n]) -> blocked fp16 layout ----------------
// dst[(ctg*(C/32)+s)*512 + quad*128 + m*8 + j]  where n = ctg*16+m, k = s*32+quad*8+j
__global__ void w2tt_kernel(const float* __restrict__ w2, unsigned short* __restrict__ w2t, int C) {
    int idx = blockIdx.x * 256 + threadIdx.x;
    if (idx >= C * C) return;
    int k = idx / C, n = idx % C;
    int dst = ((n >> 4) * (C / 32) + (k >> 5)) * 512 + ((k >> 3) & 3) * 128 + (n & 15) * 8 + (k & 7);
    w2t[dst] = f2h(w2[idx]);
}

// ---------------- Edge MLP2 + scatter-max ----------------
template<int C, int W>
__global__ __launch_bounds__(W * 64, 4) void edge_kernel(const float* __restrict__ U, const float* __restrict__ P,
                                                         const int* __restrict__ knn, const unsigned short* __restrict__ w2t,
                                                         const float* __restrict__ b2, float* __restrict__ Y) {
    constexpr int NCT = C / (W * 16);    // col tiles per wave
    constexpr int EPT = 32 / W;          // staging cols per thread (8 or 4)
    constexpr int S = C / 32;            // k-chunks
    __shared__ unsigned short Tb[2][64 * 40];   // double-buffered 64 x (32+8 pad) halves
    __shared__ int jn[64];
    const int i = blockIdx.x;
    const int tid = threadIdx.x;
    const int wave = tid >> 6, lane = tid & 63, m = lane & 15, quad = lane >> 4;
    const int cw = wave * (NCT * 16);
    if (tid < 64) jn[tid] = knn[(size_t)i * KNN + tid];
    f32x4 acc[4][NCT];
    f32x4 zero = {0.f, 0.f, 0.f, 0.f};
    #pragma unroll
    for (int rt = 0; rt < 4; ++rt)
        #pragma unroll
        for (int ct = 0; ct < NCT; ++ct)
            acc[rt][ct] = zero;
    const int rr = tid / W;              // staging row 0..63
    const int c0 = (tid % W) * EPT;      // staging col base
    __syncthreads();                     // jn visible
    const float* up = U + (size_t)jn[rr] * C + c0;
    const float* pp = P + (size_t)i * C + c0;
    float4 u0, u1, p0, p1;
    u0 = ((const float4*)up)[0]; p0 = ((const float4*)pp)[0];
    if constexpr (EPT == 8) { u1 = ((const float4*)up)[1]; p1 = ((const float4*)pp)[1]; }
    #pragma unroll 2
    for (int s = 0; s < S; ++s) {
        unsigned short* tb = Tb[s & 1];
        if constexpr (EPT == 8) {
            uint4 pk;
            pk.x = (unsigned)f2h(fmaxf(u0.x - p0.x, 0.f)) | ((unsigned)f2h(fmaxf(u0.y - p0.y, 0.f)) << 16);
            pk.y = (unsigned)f2h(fmaxf(u0.z - p0.z, 0.f)) | ((unsigned)f2h(fmaxf(u0.w - p0.w, 0.f)) << 16);
            pk.z = (unsigned)f2h(fmaxf(u1.x - p1.x, 0.f)) | ((unsigned)f2h(fmaxf(u1.y - p1.y, 0.f)) << 16);
            pk.w = (unsigned)f2h(fmaxf(u1.z - p1.z, 0.f)) | ((unsigned)f2h(fmaxf(u1.w - p1.w, 0.f)) << 16);
            *(uint4*)&tb[rr * 40 + c0] = pk;
        } else {
            uint2 pk;
            pk.x = (unsigned)f2h(fmaxf(u0.x - p0.x, 0.f)) | ((unsigned)f2h(fmaxf(u0.y - p0.y, 0.f)) << 16);
            pk.y = (unsigned)f2h(fmaxf(u0.z - p0.z, 0.f)) | ((unsigned)f2h(fmaxf(u0.w - p0.w, 0.f)) << 16);
            *(uint2*)&tb[rr * 40 + c0] = pk;
        }
        if (s + 1 < S) {                 // prefetch next chunk; latency overlaps barrier+MFMA
            u0 = ((const float4*)(up + (s + 1) * 32))[0];
            p0 = ((const float4*)(pp + (s + 1) * 32))[0];
            if constexpr (EPT == 8) {
                u1 = ((const float4*)(up + (s + 1) * 32))[1];
                p1 = ((const float4*)(pp + (s + 1) * 32))[1];
            }
        }
        __syncthreads();
        f16x8 a[4];
        #pragma unroll
        for (int rt = 0; rt < 4; ++rt)
            a[rt] = *(const f16x8*)&tb[(rt * 16 + m) * 40 + quad * 8];
        #pragma unroll
        for (int ct = 0; ct < NCT; ++ct) {
            const f16x8 bb = *(const f16x8*)(w2t +
                (size_t)(((cw >> 4) + ct) * (C / 32) + s) * 512 + quad * 128 + m * 8);
            #pragma unroll
            for (int rt = 0; rt < 4; ++rt)
                acc[rt][ct] = __builtin_amdgcn_mfma_f32_16x16x32_f16(a[rt], bb, acc[rt][ct], 0, 0, 0);
        }
    }
    #pragma unroll
    for (int ct = 0; ct < NCT; ++ct) {
        float vmax = -3.4e38f;
        #pragma unroll
        for (int rt = 0; rt < 4; ++rt) {
            vmax = fmaxf(vmax, acc[rt][ct][0]);
            vmax = fmaxf(vmax, acc[rt][ct][1]);
            vmax = fmaxf(vmax, acc[rt][ct][2]);
            vmax = fmaxf(vmax, acc[rt][ct][3]);
        }
        vmax = fmaxf(vmax, __shfl_xor(vmax, 16));
        vmax = fmaxf(vmax, __shfl_xor(vmax, 32));
        if (quad == 0) {
            int col = cw + ct * 16 + m;
            Y[(size_t)i * C + col] = vmax + b2[col];
        }
    }
}

// ---------------- Classifier: [N,512] @ [512,14] + b ----------------
__global__ __launch_bounds__(256) void cls_kernel(const float* __restrict__ h, const float* __restrict__ w,
                                                  const float* __restrict__ bias, float* __restrict__ out) {
    __shared__ float wl[512 * 14];
    int tid = threadIdx.x;
    for (int idx = tid; idx < 512 * 14; idx += 256) wl[idx] = w[idx];
    __syncthreads();
    if (tid < 224) {
        int nl = tid / 14, c = tid - nl * 14;
        int n = blockIdx.x * 16 + nl;
        float acc = bias[c];
        const float* hr = h + (size_t)n * 512;
        for (int k = 0; k < 512; ++k)
            acc += hr[k] * wl[k * 14 + c];
        out[(size_t)n * 14 + c] = acc;
    }
}

extern "C" void kernel_launch(void* const* d_in, const int* in_sizes, int n_in,
                              void* d_out, int out_size, void* d_ws, size_t ws_size,
                              hipStream_t stream) {
    const float* pos = (const float*)d_in[0];
    const float* gnw[6]; const float* gnb[6]; const float* gnms[6];
    for (int i = 0; i < 6; ++i) {
        gnw[i]  = (const float*)d_in[2 + 3 * i];
        gnb[i]  = (const float*)d_in[3 + 3 * i];
        gnms[i] = (const float*)d_in[4 + 3 * i];
    }
    const float* cw1[5]; const float* cb1[5]; const float* cw2[5]; const float* cb2[5];
    for (int i = 0; i < 5; ++i) {
        cw1[i] = (const float*)d_in[20 + 4 * i];
        cb1[i] = (const float*)d_in[21 + 4 * i];
        cw2[i] = (const float*)d_in[22 + 4 * i];
        cb2[i] = (const float*)d_in[23 + 4 * i];
    }
    const float* clsw = (const float*)d_in[40];
    const float* clsb = (const float*)d_in[41];
    float* out = (float*)d_out;

    char* ws = (char*)d_ws;
    int* knn            = (int*)(ws + 0);                 // 1 MB
    float* U            = (float*)(ws + 1048576);         // 8 MB
    float* P            = (float*)(ws + 9437184);         // 8 MB
    float* h            = (float*)(ws + 17825792);        // 8 MB
    float* y            = (float*)(ws + 26214400);        // 8 MB
    unsigned short* w2t = (unsigned short*)(ws + 34635776); // 512 KB

    knn_kernel<<<N_NODES, 256, 0, stream>>>(pos, knn);

    // gn1 on pos -> h [N,3] (no relu)
    gn_fused<<<dim3(1, NGRAPH), 256, 0, stream>>>(pos, gnms[0], gnw[0], gnb[0], 3, h, 0);

    // Layer 1: CIN=3, C=64
    node_kernel<3, 64><<<N_NODES / 16, 64, 0, stream>>>(h, pos, cw1[0], cb1[0], U, P);
    w2tt_kernel<<<(64 * 64 + 255) / 256, 256, 0, stream>>>(cw2[0], w2t, 64);
    edge_kernel<64, 4><<<N_NODES, 256, 0, stream>>>(U, P, knn, w2t, cb2[0], y);
    gn_fused<<<dim3(1, NGRAPH), 256, 0, stream>>>(y, gnms[1], gnw[1], gnb[1], 64, h, 1);

    // Layer 2: CIN=64, C=128
    node_kernel<64, 128><<<N_NODES / 16, 128, 0, stream>>>(h, pos, cw1[1], cb1[1], U, P);
    w2tt_kernel<<<(128 * 128 + 255) / 256, 256, 0, stream>>>(cw2[1], w2t, 128);
    edge_kernel<128, 8><<<N_NODES, 512, 0, stream>>>(U, P, knn, w2t, cb2[1], y);
    gn_fused<<<dim3(2, NGRAPH), 256, 0, stream>>>(y, gnms[2], gnw[2], gnb[2], 128, h, 1);

    // Layer 3: CIN=128, C=256
    node_kernel<128, 256><<<N_NODES / 16, 256, 0, stream>>>(h, pos, cw1[2], cb1[2], U, P);
    w2tt_kernel<<<(256 * 256 + 255) / 256, 256, 0, stream>>>(cw2[2], w2t, 256);
    edge_kernel<256, 8><<<N_NODES, 512, 0, stream>>>(U, P, knn, w2t, cb2[2], y);
    gn_fused<<<dim3(4, NGRAPH), 256, 0, stream>>>(y, gnms[3], gnw[3], gnb[3], 256, h, 1);

    // Layer 4: CIN=256, C=512
    node_kernel<256, 512><<<N_NODES / 16, 512, 0, stream>>>(h, pos, cw1[3], cb1[3], U, P);
    w2tt_kernel<<<(512 * 512 + 255) / 256, 256, 0, stream>>>(cw2[3], w2t, 512);
    edge_kernel<512, 8><<<N_NODES, 512, 0, stream>>>(U, P, knn, w2t, cb2[3], y);
    gn_fused<<<dim3(8, NGRAPH), 256, 0, stream>>>(y, gnms[4], gnw[4], gnb[4], 512, h, 1);

    // Layer 5: CIN=512, C=512
    node_kernel<512, 512><<<N_NODES / 16, 512, 0, stream>>>(h, pos, cw1[4], cb1[4], U, P);
    w2tt_kernel<<<(512 * 512 + 255) / 256, 256, 0, stream>>>(cw2[4], w2t, 512);
    edge_kernel<512, 8><<<N_NODES, 512, 0, stream>>>(U, P, knn, w2t, cb2[4], y);
    gn_fused<<<dim3(8, NGRAPH), 256, 0, stream>>>(y, gnms[5], gnw[5], gnb[5], 512, h, 1);

    cls_kernel<<<N_NODES / 16, 256, 0, stream>>>(h, clsw, clsb, out);
}